// Round 10
// baseline (1011.425 us; speedup 1.0000x reference)
//
#include <hip/hip_runtime.h>
#include <hip/hip_bf16.h>
#include <math.h>

// T=10 B=512 N_ALL=23 N_AGENTS=22 NH=8 E=506 RNN_H=64 Z_DIM=92 IN_H=1592
// R6 3-kernel schedule + MFMA heads (bf16, BN3 folded into weights, no split-K):
//   K1(t) = headsMFMA(t)[32] + edges(t-1)[512]
//   K2(t) = fused(t)[46] + node3(t-1)[46]
//   K3(t) = gru(t)[352, writes h fp32 + bf16] + dec(t-1)[352]

typedef __attribute__((ext_vector_type(8))) short s16x8;
typedef __attribute__((ext_vector_type(4))) float f32x4;

__device__ __forceinline__ unsigned short f2bf(float x){
  __hip_bfloat16 b = __float2bfloat16(x);
  return *reinterpret_cast<unsigned short*>(&b);
}
__device__ __forceinline__ float elu_(float x){ return x>0.f ? x : __expf(x)-1.f; }
__device__ __forceinline__ float sp_(float x){ return fmaxf(x,0.f)+log1pf(__expf(-fabsf(x))); }
__device__ __forceinline__ float sig_(float x){ return 1.f/(1.f+__expf(-x)); }
__device__ __forceinline__ float wsum_(float v){
  #pragma unroll
  for (int o=32;o;o>>=1) v += __shfl_down(v,o,64);
  return v;
}

__device__ __forceinline__ void reduce_bn_(const float* __restrict__ part, int n,
    float invN, const float* __restrict__ gam, const float* __restrict__ bet,
    float* sc, float* sh, float* tmp)
{
  int tid = threadIdx.x;
  int c = tid & 15, i0 = tid >> 4;
  float s = 0.f;
  for (int i = i0; i < n; i += 16) s += part[i*16 + c];
  tmp[i0*16 + c] = s;
  __syncthreads();
  if (tid < 16){
    float v = 0.f;
    #pragma unroll
    for (int i=0;i<16;i++) v += tmp[i*16 + tid];
    tmp[tid] = v;
  }
  __syncthreads();
  if (tid < 8){
    float m = tmp[tid]*invN;
    float var = tmp[8+tid]*invN - m*m;
    float rs = rsqrtf(var + 1e-5f);
    float s2 = rs*gam[tid];
    sc[tid] = s2; sh[tid] = bet[tid] - m*s2;
  }
  __syncthreads();
}

__device__ __forceinline__ void block_stats_(const float h[8], float* __restrict__ part,
                                             float red[][16])
{
  int wid = threadIdx.x >> 6, lane = threadIdx.x & 63;
  #pragma unroll
  for (int j=0;j<8;j++){
    float a = wsum_(h[j]);
    float b = wsum_(h[j]*h[j]);
    if (lane==0){ red[wid][j]=a; red[wid][8+j]=b; }
  }
  __syncthreads();
  if (threadIdx.x < 16)
    part[threadIdx.x] = red[0][threadIdx.x]+red[1][threadIdx.x]
                       +red[2][threadIdx.x]+red[3][threadIdx.x];
}

// ================= scan device blocks (256 threads) =================

// MFMA heads: one block = (head, 64-row M-tile); 4 waves x 16 rows; full K.
__device__ __forceinline__ void dev_heads_mfma(
    int idx, int t,
    const unsigned short* __restrict__ g3b,  // [20][512][192] bf16 (pre-BN3)
    const unsigned short* __restrict__ hb,   // [22][512][64]  bf16
    const unsigned short* __restrict__ Wbt,  // [10][4][96][192] bf16 (BN3-scaled)
    const unsigned short* __restrict__ Wbs,  // [4][96][1408] bf16
    const float* __restrict__ cst,           // [10][4][96]
    float* __restrict__ raw)                 // [4][512][92]
{
  int head = idx & 3, mb = idx >> 2;         // mb in [0,8)
  int tid = threadIdx.x;
  int wv = tid >> 6, lane = tid & 63;
  int m0 = mb*64 + wv*16;
  int rloc = lane & 15, kg = lane >> 4;
  int row = m0 + rloc;
  int selg = (head < 2) ? t : 10 + t;
  const unsigned short* Ag = g3b + (size_t)selg*98304 + (size_t)row*192 + kg*8;
  const unsigned short* Wt = Wbt + (size_t)((t*4+head)*96)*192 + kg*8;
  const unsigned short* Wsb = Wbs + (size_t)head*135168;
  f32x4 cd[6];
  #pragma unroll
  for (int n=0;n<6;n++) cd[n] = (f32x4){0.f,0.f,0.f,0.f};
  // region 1: f in [0,192): 6 K-steps (BN3-scaled weights)
  #pragma unroll
  for (int ks=0; ks<6; ks++){
    s16x8 af = *(const s16x8*)(Ag + ks*32);
    #pragma unroll
    for (int n=0;n<6;n++){
      int col = n*16 + rloc;
      s16x8 bf = *(const s16x8*)(Wt + (size_t)col*192 + ks*32);
      cd[n] = __builtin_amdgcn_mfma_f32_16x16x32_bf16(af, bf, cd[n], 0,0,0);
    }
  }
  // region 2: f2 in [0,1408): 44 K-steps (h state)
  const unsigned short* Ah = hb + (size_t)row*64;
  #pragma unroll 4
  for (int ks=0; ks<44; ks++){
    int f2 = ks*32 + kg*8;
    s16x8 af = *(const s16x8*)(Ah + (size_t)(f2>>6)*32768 + (f2&63));
    #pragma unroll
    for (int n=0;n<6;n++){
      int col = n*16 + rloc;
      s16x8 bf = *(const s16x8*)(Wsb + (size_t)col*1408 + f2);
      cd[n] = __builtin_amdgcn_mfma_f32_16x16x32_bf16(af, bf, cd[n], 0,0,0);
    }
  }
  float* dst = raw + (size_t)head*47104;
  const float* cb = cst + (size_t)(t*4+head)*96;
  #pragma unroll
  for (int n=0;n<6;n++){
    int col = n*16 + rloc;
    if (col < 92){
      float cc = cb[col];
      #pragma unroll
      for (int r=0;r<4;r++){
        int rr = m0 + (kg<<2) + r;   // C/D: col=lane&15, row=(lane>>4)*4+reg
        dst[(size_t)rr*92 + col] = cd[n][r] + cc;
      }
    }
  }
}

// edges (256 thr, smem 5274 fl): BN1-reduce(46), node MLP1+BN1, edge MLP once,
// receiver pre-BN sums + BN2 stats partials. Reads z from zb.
__device__ __forceinline__ void dev_edges(
    float* smem, int b, const float* __restrict__ zb, const float* __restrict__ p1,
    const float* __restrict__ nW1, const float* __restrict__ nb1,
    const float* __restrict__ nW2, const float* __restrict__ nb2,
    const float* __restrict__ g1, const float* __restrict__ bt1,
    const float* __restrict__ eW1, const float* __restrict__ eb1,
    const float* __restrict__ eW2, const float* __restrict__ eb2,
    float* __restrict__ zna, float* __restrict__ zp2)
{
  int tid = threadIdx.x;
  float* tmp   = smem;        // 256
  float* sc1   = smem+256;    // 8
  float* sh1   = smem+264;    // 8
  float* xnode = smem+272;    // 207
  float* accs  = smem+480;    // 207
  float* redsq = smem+688;    // 32
  float* le    = smem+720;    // 4554
  {
    int c = tid & 15, i0 = tid >> 4;
    float s = 0.f;
    for (int i=i0;i<46;i+=16) s += p1[i*16+c];
    tmp[i0*16+c] = s;
    __syncthreads();
    if (tid<16){
      float v=0.f;
      #pragma unroll
      for (int i=0;i<16;i++) v += tmp[i*16+tid];
      tmp[tid]=v;
    }
    __syncthreads();
    if (tid<8){
      float m = tmp[tid]*(1.f/11776.f);
      float var = tmp[8+tid]*(1.f/11776.f) - m*m;
      float rs = rsqrtf(var+1e-5f);
      float s2 = rs*g1[tid];
      sc1[tid]=s2; sh1[tid]=bt1[tid]-m*s2;
    }
    __syncthreads();
  }
  if (tid<23){
    const float* x = zb + (size_t)b*92 + tid*4;
    float x0=x[0],x1=x[1],x2=x[2],x3=x[3];
    float h1[8];
    #pragma unroll
    for (int j=0;j<8;j++)
      h1[j]=elu_(nb1[j]+nW1[j*4]*x0+nW1[j*4+1]*x1+nW1[j*4+2]*x2+nW1[j*4+3]*x3);
    #pragma unroll
    for (int j=0;j<8;j++){
      float a=nb2[j];
      #pragma unroll
      for (int k=0;k<8;k++) a+=nW2[j*8+k]*h1[k];
      xnode[tid*9+j]=elu_(a)*sc1[j]+sh1[j];
    }
  }
  __syncthreads();
  float sq[8]={0,0,0,0,0,0,0,0};
  for (int e=tid; e<506; e+=256){
    int r=e/22, jj=e-r*22;
    int s=jj+(jj>=r?1:0);
    float et0=(jj==0 && r>=1 && r<=21)?1.f:0.f;
    float et1=(r==22)?1.f:0.f;
    float xs[8], xr[8];
    #pragma unroll
    for (int k=0;k<8;k++){ xs[k]=xnode[s*9+k]; xr[k]=xnode[r*9+k]; }
    float h1[8];
    #pragma unroll
    for (int j=0;j<8;j++){
      const float* w=eW1+j*18;
      float a=eb1[j]+w[16]*et0+w[17]*et1;
      #pragma unroll
      for (int k=0;k<8;k++) a+=w[k]*xs[k];
      #pragma unroll
      for (int k=0;k<8;k++) a+=w[8+k]*xr[k];
      h1[j]=elu_(a);
    }
    #pragma unroll
    for (int j=0;j<8;j++){
      float a=eb2[j];
      #pragma unroll
      for (int k=0;k<8;k++) a+=eW2[j*8+k]*h1[k];
      float h2=elu_(a);
      le[e*9+j]=h2;
      sq[j]+=h2*h2;
    }
  }
  int wid=tid>>6, lane=tid&63;
  #pragma unroll
  for (int j=0;j<8;j++){
    float v=wsum_(sq[j]);
    if (lane==0) redsq[wid*8+j]=v;
  }
  __syncthreads();
  if (tid<184){
    int r=tid>>3, c=tid&7;
    const float* lp = le + r*198 + c;
    float s=0.f;
    #pragma unroll
    for (int jj=0;jj<22;jj++) s+=lp[jj*9];
    accs[r*9+c]=s;
    zna[(size_t)b*184+tid]=s;
  }
  __syncthreads();
  if (tid<16){
    int c=tid&7;
    float s=0.f;
    if (tid<8){
      #pragma unroll
      for (int r=0;r<23;r++) s+=accs[r*9+c];
    } else {
      #pragma unroll
      for (int w=0;w<4;w++) s+=redsq[w*8+c];
    }
    zp2[(size_t)b*16+tid]=s;
  }
}

// node3 (smem 336 fl); fp32 out (scan) or bf16 out (precompute)
__device__ __forceinline__ void dev_node3(
    float* smem, int bi, int g, int p,
    const float* __restrict__ nodeacc, const float* __restrict__ p2,
    const float* __restrict__ g2b, const float* __restrict__ bt2b,
    const float* __restrict__ W3b, const float* __restrict__ b3b,
    const float* __restrict__ W4b, const float* __restrict__ b4b,
    float* __restrict__ outf, unsigned short* __restrict__ outb,
    float* __restrict__ p3)
{
  float* tmp = smem; float* sc2 = smem+256; float* sh2 = smem+264;
  float (*red)[16] = (float(*)[16])(smem+272);
  reduce_bn_(p2 + (size_t)g*8192, 512, 1.f/259072.f, g2b+p*8, bt2b+p*8, sc2, sh2, tmp);
  int row = bi*256 + threadIdx.x;
  int b = row/23, r = row - b*23;
  const float inv23 = 1.f/23.f;
  const float* na = nodeacc + ((size_t)g*512 + b)*184 + r*8;
  float xk[8];
  #pragma unroll
  for (int k=0;k<8;k++) xk[k] = (na[k]*sc2[k] + 22.f*sh2[k]) * inv23;
  float nt0 = (r<22)?inv23:0.f, nt1 = (r==22)?inv23:0.f;
  const float* W3 = W3b + p*80; const float* b3 = b3b + p*8;
  const float* W4 = W4b + p*64; const float* b4 = b4b + p*8;
  float h1b[8], o[8];
  #pragma unroll
  for (int j=0;j<8;j++){
    const float* w = W3 + j*10;
    float a = b3[j] + w[8]*nt0 + w[9]*nt1;
    #pragma unroll
    for (int k=0;k<8;k++) a += w[k]*xk[k];
    h1b[j] = elu_(a);
  }
  #pragma unroll
  for (int j=0;j<8;j++){
    float a = b4[j];
    #pragma unroll
    for (int k=0;k<8;k++) a += W4[j*8+k]*h1b[k];
    o[j] = elu_(a);
    if (outf) outf[(size_t)row*8 + j] = o[j];
    else outb[(size_t)g*98304 + (size_t)b*192 + r*8 + j] = f2bf(o[j]);
  }
  block_stats_(o, p3 + ((size_t)g*46 + bi)*16, red);
}

// fused (smem 68 fl): bias + sample + KLD + MLP1(set2) stats; single raw
__device__ __forceinline__ void dev_fused(
    float* smem, int bi,
    const float* __restrict__ raw,
    const float* __restrict__ bpm, const float* __restrict__ bps,
    const float* __restrict__ bem, const float* __restrict__ bes,
    const float* __restrict__ eps_t, float* __restrict__ z,
    float* __restrict__ lklp,
    const float* __restrict__ W1, const float* __restrict__ b1,
    const float* __restrict__ W2, const float* __restrict__ b2,
    float* __restrict__ part)
{
  float* redk = smem;
  float (*red)[16] = (float(*)[16])(smem+4);
  int tid = threadIdx.x;
  int row = bi*256 + tid;                            // [0, 11776)
  int bb = row/23, n = row - bb*23;
  (void)bb;
  float4 a  = *(const float4*)(raw + 4*(size_t)row);
  float4 bq = *(const float4*)(raw + 47104 + 4*(size_t)row);
  float4 c  = *(const float4*)(raw + 94208 + 4*(size_t)row);
  float4 d  = *(const float4*)(raw + 141312 + 4*(size_t)row);
  float pm[4]={a.x,a.y,a.z,a.w}, ps[4]={bq.x,bq.y,bq.z,bq.w};
  float em[4]={c.x,c.y,c.z,c.w}, es[4]={d.x,d.y,d.z,d.w};
  int j0 = 4*n;
  float4 e4 = *(const float4*)(eps_t + 4*(size_t)row);
  float ev[4] = {e4.x, e4.y, e4.z, e4.w};
  float zv[4]; float kl = 0.f;
  #pragma unroll
  for (int q=0;q<4;q++){
    float PM = pm[q] + bpm[j0+q];
    float PS = sp_(ps[q] + bps[j0+q]);
    float EM = em[q] + bem[j0+q];
    float ES = sp_(es[q] + bes[j0+q]);
    zv[q] = EM + ES*ev[q];
    float dd = EM - PM;
    kl += 0.5f*(2.f*logf(PS/ES) + (ES*ES + dd*dd)/(PS*PS) - 1.f);
  }
  float4 zq; zq.x=zv[0]; zq.y=zv[1]; zq.z=zv[2]; zq.w=zv[3];
  *(float4*)(z + 4*(size_t)row) = zq;
  float ks = wsum_(kl);
  if ((tid&63)==0) redk[tid>>6] = ks;
  __syncthreads();
  if (tid==0) lklp[bi] = redk[0]+redk[1]+redk[2]+redk[3];
  float h1[8], h2[8];
  #pragma unroll
  for (int j=0;j<8;j++){
    float av = b1[j] + W1[j*4+0]*zv[0] + W1[j*4+1]*zv[1] + W1[j*4+2]*zv[2] + W1[j*4+3]*zv[3];
    h1[j] = elu_(av);
  }
  #pragma unroll
  for (int j=0;j<8;j++){
    float av = b2[j];
    #pragma unroll
    for (int k=0;k<8;k++) av += W2[j*8+k]*h1[k];
    h2[j] = elu_(av);
  }
  block_stats_(h2, part + (size_t)bi*16, red);
}

// dec (smem 520 fl)
__device__ __forceinline__ void dev_dec(
    float* smem, int bi,
    const float* __restrict__ zg3, const float* __restrict__ p3,
    const float* __restrict__ gam, const float* __restrict__ bet,
    const float* __restrict__ Wm, const float* __restrict__ Bm,
    const float* __restrict__ Wsd, const float* __restrict__ Bsd,
    float* __restrict__ odm, float* __restrict__ ods)
{
  int tid = threadIdx.x;
  float* dtmp = smem; float* dsc = smem + 256; float* dsh = smem + 264;
  reduce_bn_(p3, 46, 1.f/11776.f, gam, bet, dsc, dsh, dtmp);
  float4 s0 = {dsc[0],dsc[1],dsc[2],dsc[3]};
  float4 s1 = {dsc[4],dsc[5],dsc[6],dsc[7]};
  float4 t0 = {dsh[0],dsh[1],dsh[2],dsh[3]};
  float4 t1 = {dsh[4],dsh[5],dsh[6],dsh[7]};
  int idx = bi*256 + tid;
  int hd = idx / 45056; int rem = idx - hd*45056;
  int b = rem / 88, j = rem - b*88;
  const float* W = hd ? Wsd : Wm;
  const float4* a4 = (const float4*)(zg3 + (size_t)b*184);
  const float4* w4 = (const float4*)(W + (size_t)j*184);
  float accv = hd ? Bsd[j] : Bm[j];
  #pragma unroll 2
  for (int i4=0;i4<46;i4++){
    float4 x = a4[i4]; float4 w = w4[i4];
    float4 sc = (i4&1)? s1 : s0; float4 sh = (i4&1)? t1 : t0;
    accv += w.x*(x.x*sc.x+sh.x) + w.y*(x.y*sc.y+sh.y)
          + w.z*(x.z*sc.z+sh.z) + w.w*(x.w*sc.w+sh.w);
  }
  if (hd) ods[(size_t)b*88+j] = sp_(accv);
  else    odm[(size_t)b*88+j] = accv;
}

// gru (smem 14944 fl): conflict-free transposed weights; writes h fp32 + bf16
__device__ __forceinline__ void dev_gru(
    float* smem, int idx,
    float* __restrict__ h, unsigned short* __restrict__ hbf,
    const float* __restrict__ x_t,
    const float* __restrict__ z, const float* __restrict__ Wih,
    const float* __restrict__ Whh, const float* __restrict__ bih,
    const float* __restrict__ bhh)
{
  int tid = threadIdx.x;
  float* WhT  = smem;           // 64*193 = 12352
  float* hs   = smem + 12352;   // 64*36  = 2304
  float* gins = smem + 14656;   // 8*36   = 288
  int a = idx >> 4, yb = idx & 15;
  int b0 = yb*32;
  int c = tid & 63, sq = tid >> 6;
  const float* Wg = Whh + (size_t)a*12288;
  for (int e = tid; e < 12288; e += 256) WhT[(e&63)*193 + (e>>6)] = Wg[e];
  const float* hp_g = h + (size_t)a*32768 + (size_t)b0*64;
  for (int e = tid; e < 2048; e += 256) hs[(e&63)*36 + (e>>6)] = hp_g[e];
  { int s = tid >> 3, k = tid & 7;
    float v = (k<4) ? x_t[(size_t)(b0+s)*92 + a*4 + k]
                    : z[(size_t)(b0+s)*92 + a*4 + (k-4)];
    gins[k*36 + s] = v; }
  float wi0[8], wi1[8], wi2[8];
  const float* Wig = Wih + (size_t)a*1536;
  #pragma unroll
  for (int k=0;k<8;k++){
    wi0[k] = Wig[c*8+k]; wi1[k] = Wig[(64+c)*8+k]; wi2[k] = Wig[(128+c)*8+k];
  }
  float bi0 = bih[a*192+c], bi1 = bih[a*192+64+c], bi2 = bih[a*192+128+c];
  float bh0 = bhh[a*192+c], bh1 = bhh[a*192+64+c], bh2 = bhh[a*192+128+c];
  __syncthreads();
  #pragma unroll
  for (int ps=0; ps<2; ps++){
    int s0 = ps*16 + sq*4;
    float q0[4], q1[4], q2[4];
    #pragma unroll
    for (int i=0;i<4;i++){ q0[i]=bh0; q1[i]=bh1; q2[i]=bh2; }
    for (int k=0;k<64;k++){
      float w0 = WhT[k*193 + c];
      float w1 = WhT[k*193 + 64 + c];
      float w2 = WhT[k*193 + 128 + c];
      float4 hv = *(const float4*)&hs[k*36 + s0];
      float hvv[4] = {hv.x,hv.y,hv.z,hv.w};
      #pragma unroll
      for (int i=0;i<4;i++){ q0[i]+=w0*hvv[i]; q1[i]+=w1*hvv[i]; q2[i]+=w2*hvv[i]; }
    }
    float g0[4], g1[4], g2[4];
    #pragma unroll
    for (int i=0;i<4;i++){ g0[i]=bi0; g1[i]=bi1; g2[i]=bi2; }
    #pragma unroll
    for (int k=0;k<8;k++){
      float4 gv = *(const float4*)&gins[k*36 + s0];
      float gvv[4] = {gv.x,gv.y,gv.z,gv.w};
      #pragma unroll
      for (int i=0;i<4;i++){ g0[i]+=wi0[k]*gvv[i]; g1[i]+=wi1[k]*gvv[i]; g2[i]+=wi2[k]*gvv[i]; }
    }
    float4 hp = *(const float4*)&hs[c*36 + s0];
    float hpv[4] = {hp.x,hp.y,hp.z,hp.w};
    #pragma unroll
    for (int i=0;i<4;i++){
      float rg = sig_(g0[i]+q0[i]);
      float zg = sig_(g1[i]+q1[i]);
      float ng = tanhf(g2[i] + rg*q2[i]);
      float hn = (1.f-zg)*ng + zg*hpv[i];
      size_t off = (size_t)a*32768 + (size_t)(b0+s0+i)*64 + c;
      h[off] = hn;
      hbf[off] = f2bf(hn);
    }
  }
}

// ================= precompute kernels =================

__global__ __launch_bounds__(256) void k_stats1(
    const float* __restrict__ states,
    const float* __restrict__ W1b, const float* __restrict__ b1b,
    const float* __restrict__ W2b, const float* __restrict__ b2b,
    float* __restrict__ part)
{
  int g = blockIdx.y; int p = g/10; int t = g - p*10;
  const float* W1 = W1b + p*32; const float* b1 = b1b + p*8;
  const float* W2 = W2b + p*64; const float* b2 = b2b + p*8;
  int row = blockIdx.x*256 + threadIdx.x;
  float4 x4 = *(const float4*)(states + (size_t)(t+p)*47104 + 4*(size_t)row);
  float h1[8], h2[8];
  #pragma unroll
  for (int j=0;j<8;j++)
    h1[j] = elu_(b1[j] + W1[j*4+0]*x4.x + W1[j*4+1]*x4.y + W1[j*4+2]*x4.z + W1[j*4+3]*x4.w);
  #pragma unroll
  for (int j=0;j<8;j++){
    float a = b2[j];
    #pragma unroll
    for (int k=0;k<8;k++) a += W2[j*8+k]*h1[k];
    h2[j] = elu_(a);
  }
  __shared__ float red[4][16];
  block_stats_(h2, part + ((size_t)g*46 + blockIdx.x)*16, red);
}

__global__ __launch_bounds__(512) void k_pre_edges(
    const float* __restrict__ src, const float* __restrict__ p1,
    const float* __restrict__ nW1b, const float* __restrict__ nb1b,
    const float* __restrict__ nW2b, const float* __restrict__ nb2b,
    const float* __restrict__ g1b, const float* __restrict__ bt1b,
    const float* __restrict__ eW1b, const float* __restrict__ eb1b,
    const float* __restrict__ eW2b, const float* __restrict__ eb2b,
    float* __restrict__ nodeacc, float* __restrict__ p2)
{
  int g = blockIdx.y; int p = g/10; int t = g - p*10; int b = blockIdx.x;
  int tid = threadIdx.x;
  __shared__ float tmp[512];
  __shared__ float sc1[8], sh1[8];
  __shared__ float xnode[207];
  __shared__ float le[4554];
  __shared__ float accs[207];
  __shared__ float redsq[8][8];
  {
    const float* pp = p1 + (size_t)g*736;
    int c = tid & 15, i0 = tid >> 4;
    float s = 0.f;
    for (int i = i0; i < 46; i += 32) s += pp[i*16 + c];
    tmp[i0*16 + c] = s;
    __syncthreads();
    if (tid < 16){
      float v = 0.f;
      #pragma unroll
      for (int i=0;i<32;i++) v += tmp[i*16 + tid];
      tmp[tid] = v;
    }
    __syncthreads();
    if (tid < 8){
      float m = tmp[tid]*(1.f/11776.f);
      float var = tmp[8+tid]*(1.f/11776.f) - m*m;
      float rs = rsqrtf(var + 1e-5f);
      float s2 = rs*g1b[p*8+tid];
      sc1[tid] = s2; sh1[tid] = bt1b[p*8+tid] - m*s2;
    }
    __syncthreads();
  }
  if (tid < 23){
    const float* x = src + (size_t)(t+p)*47104 + (size_t)b*92 + tid*4;
    const float* W1 = nW1b + p*32; const float* b1 = nb1b + p*8;
    const float* W2 = nW2b + p*64; const float* b2 = nb2b + p*8;
    float x0=x[0], x1=x[1], x2=x[2], x3=x[3];
    float h1[8];
    #pragma unroll
    for (int j=0;j<8;j++)
      h1[j] = elu_(b1[j] + W1[j*4]*x0 + W1[j*4+1]*x1 + W1[j*4+2]*x2 + W1[j*4+3]*x3);
    #pragma unroll
    for (int j=0;j<8;j++){
      float a = b2[j];
      #pragma unroll
      for (int k=0;k<8;k++) a += W2[j*8+k]*h1[k];
      xnode[tid*9+j] = elu_(a)*sc1[j] + sh1[j];
    }
  }
  __syncthreads();
  float sq[8] = {0,0,0,0,0,0,0,0};
  if (tid < 506){
    int r = tid/22, jj = tid - r*22;
    int s = jj + (jj>=r ? 1 : 0);
    const float* W1 = eW1b + p*144; const float* b1 = eb1b + p*8;
    const float* W2 = eW2b + p*64;  const float* b2 = eb2b + p*8;
    float et0 = (jj==0 && r>=1 && r<=21) ? 1.f : 0.f;
    float et1 = (r==22) ? 1.f : 0.f;
    float h1[8];
    #pragma unroll
    for (int j=0;j<8;j++){
      const float* w = W1 + j*18;
      float a = b1[j] + w[16]*et0 + w[17]*et1;
      #pragma unroll
      for (int k=0;k<8;k++) a += w[k]*xnode[s*9+k];
      #pragma unroll
      for (int k=0;k<8;k++) a += w[8+k]*xnode[r*9+k];
      h1[j] = elu_(a);
    }
    #pragma unroll
    for (int j=0;j<8;j++){
      float a = b2[j];
      #pragma unroll
      for (int k=0;k<8;k++) a += W2[j*8+k]*h1[k];
      float h2 = elu_(a);
      le[tid*9+j] = h2;
      sq[j] = h2*h2;
    }
  }
  int wid = tid >> 6, lane = tid & 63;
  #pragma unroll
  for (int j=0;j<8;j++){
    float v = wsum_(sq[j]);
    if (lane==0) redsq[wid][j] = v;
  }
  __syncthreads();
  if (tid < 184){
    int r = tid >> 3, c = tid & 7;
    const float* lp = le + r*198 + c;
    float s = 0.f;
    #pragma unroll
    for (int jj=0;jj<22;jj++) s += lp[jj*9];
    accs[r*9+c] = s;
    nodeacc[((size_t)g*512 + b)*184 + tid] = s;
  }
  __syncthreads();
  if (tid < 16){
    int c = tid & 7;
    float s = 0.f;
    if (tid < 8){
      #pragma unroll
      for (int r=0;r<23;r++) s += accs[r*9+c];
    } else {
      #pragma unroll
      for (int w=0;w<8;w++) s += redsq[w][c];
    }
    p2[((size_t)g*512 + b)*16 + tid] = s;
  }
}

__global__ __launch_bounds__(256) void k_pre_node3(
    const float* __restrict__ nodeacc, const float* __restrict__ p2,
    const float* __restrict__ g2, const float* __restrict__ bt2,
    const float* __restrict__ W3, const float* __restrict__ b3,
    const float* __restrict__ W4, const float* __restrict__ b4,
    unsigned short* __restrict__ g3b, float* __restrict__ p3)
{
  __shared__ float smem[336];
  int g = blockIdx.y, p = g/10;
  dev_node3(smem, blockIdx.x, g, p, nodeacc, p2, g2, bt2, W3,b3,W4,b4,
            nullptr, g3b, p3);
}

__global__ __launch_bounds__(256) void k_bnred(
    const float* __restrict__ part, int n, float invN,
    const float* __restrict__ gamb, const float* __restrict__ betb,
    float* __restrict__ scsh)
{
  int g = blockIdx.x; int p = g/10;
  int tid = threadIdx.x;
  __shared__ float tmp[256];
  const float* pp = part + (size_t)g*n*16;
  int c = tid & 15, i0 = tid >> 4;
  float s = 0.f;
  for (int i = i0; i < n; i += 16) s += pp[i*16 + c];
  tmp[i0*16 + c] = s;
  __syncthreads();
  if (tid < 16){
    float v = 0.f;
    #pragma unroll
    for (int i=0;i<16;i++) v += tmp[i*16 + tid];
    tmp[tid] = v;
  }
  __syncthreads();
  if (tid < 8){
    float m = tmp[tid]*invN;
    float var = tmp[8+tid]*invN - m*m;
    float rs = rsqrtf(var + 1e-5f);
    float sc = rs*gamb[p*8+tid];
    scsh[g*16 + tid] = sc;
    scsh[g*16 + 8 + tid] = betb[p*8+tid] - m*sc;
  }
}

__global__ __launch_bounds__(256) void k_wbs(
    const float* __restrict__ Wpm, const float* __restrict__ Wps,
    const float* __restrict__ Wem, const float* __restrict__ Wes,
    unsigned short* __restrict__ Wbs)
{
  int e = blockIdx.x*256 + threadIdx.x;       // [0, 540672)
  int head = e / 135168; int rem = e - head*135168;
  int col = rem / 1408; int f2 = rem - col*1408;
  const float* W = (head==0)?Wpm:(head==1)?Wps:(head==2)?Wem:Wes;
  float v = (col<92) ? W[(size_t)col*1592 + 184 + f2] : 0.f;
  Wbs[e] = f2bf(v);
}

__global__ __launch_bounds__(256) void k_wbt(
    const float* __restrict__ Wpm, const float* __restrict__ Wps,
    const float* __restrict__ Wem, const float* __restrict__ Wes,
    const float* __restrict__ scsh3,
    unsigned short* __restrict__ Wbt)
{
  int e = blockIdx.x*256 + threadIdx.x;       // [0, 737280)
  int t = e / 73728; int rem = e - t*73728;
  int head = rem / 18432; int rem2 = rem - head*18432;
  int col = rem2 / 192; int f = rem2 - col*192;
  const float* W = (head==0)?Wpm:(head==1)?Wps:(head==2)?Wem:Wes;
  int sel = (head<2) ? t : 10+t;
  float v = (col<92 && f<184) ? W[(size_t)col*1592 + f]*scsh3[sel*16 + (f&7)] : 0.f;
  Wbt[e] = f2bf(v);
}

__global__ __launch_bounds__(256) void k_cst(
    const float* __restrict__ Wpm, const float* __restrict__ Wps,
    const float* __restrict__ Wem, const float* __restrict__ Wes,
    const float* __restrict__ scsh3, float* __restrict__ cst)
{
  int e = blockIdx.x*256 + threadIdx.x;      // [0, 3840)
  if (e >= 3840) return;
  int t = e / 384; int rem = e - t*384;
  int head = rem / 96; int col = rem - head*96;
  float s = 0.f;
  if (col < 92){
    const float* W = (head==0)?Wpm:(head==1)?Wps:(head==2)?Wem:Wes;
    int sel = (head<2) ? t : 10+t;
    const float* sh = scsh3 + sel*16 + 8;
    for (int f=0; f<184; f++) s += W[(size_t)col*1592+f]*sh[f&7];
  }
  cst[e] = s;
}

// ================= scan kernels (R6 schedule) =================

// K1(t): [0,nh) headsMFMA(t), [nh,...) edges(t-1)
__global__ __launch_bounds__(256) void k_K1(
    int nh, int t,
    const unsigned short* __restrict__ g3b, const unsigned short* __restrict__ hbf,
    const unsigned short* __restrict__ Wbt, const unsigned short* __restrict__ Wbs,
    const float* __restrict__ cst, float* __restrict__ raw,
    const float* __restrict__ zb, const float* __restrict__ zp1,
    const float* __restrict__ nW1, const float* __restrict__ nb1,
    const float* __restrict__ nW2, const float* __restrict__ nb2,
    const float* __restrict__ g1, const float* __restrict__ bt1,
    const float* __restrict__ eW1, const float* __restrict__ eb1,
    const float* __restrict__ eW2, const float* __restrict__ eb2,
    float* __restrict__ zna, float* __restrict__ zp2)
{
  __shared__ float smem[5274];
  if ((int)blockIdx.x < nh)
    dev_heads_mfma(blockIdx.x, t, g3b, hbf, Wbt, Wbs, cst, raw);
  else
    dev_edges(smem, blockIdx.x - nh, zb, zp1,
              nW1,nb1,nW2,nb2, g1,bt1, eW1,eb1,eW2,eb2, zna, zp2);
}

// K2(t): [0,nf) fused(t), [nf,...) node3(t-1)
__global__ __launch_bounds__(256) void k_K2(
    int nf,
    const float* __restrict__ raw,
    const float* __restrict__ bpm, const float* __restrict__ bps,
    const float* __restrict__ bem, const float* __restrict__ bes,
    const float* __restrict__ eps_t, float* __restrict__ z,
    float* __restrict__ lklp,
    const float* __restrict__ W1, const float* __restrict__ b1,
    const float* __restrict__ W2, const float* __restrict__ b2,
    float* __restrict__ part,
    const float* __restrict__ zna, const float* __restrict__ zp2,
    const float* __restrict__ g2, const float* __restrict__ bt2,
    const float* __restrict__ W3, const float* __restrict__ b3,
    const float* __restrict__ W4, const float* __restrict__ b4,
    float* __restrict__ zg3, float* __restrict__ zp3)
{
  __shared__ float smem[336];
  if ((int)blockIdx.x < nf)
    dev_fused(smem, blockIdx.x, raw, bpm,bps,bem,bes, eps_t, z, lklp, W1,b1,W2,b2, part);
  else
    dev_node3(smem, blockIdx.x - nf, 0, 0, zna, zp2, g2, bt2, W3,b3,W4,b4,
              zg3, nullptr, zp3);
}

// K3(t): [0,ngru) gru(t), [ngru,...) dec(t-1)
__global__ __launch_bounds__(256) void k_K3(
    int ngru,
    float* __restrict__ h, unsigned short* __restrict__ hbf,
    const float* __restrict__ x_t,
    const float* __restrict__ z, const float* __restrict__ Wih,
    const float* __restrict__ Whh, const float* __restrict__ bih,
    const float* __restrict__ bhh,
    const float* __restrict__ zg3, const float* __restrict__ p3,
    const float* __restrict__ gam, const float* __restrict__ bet,
    const float* __restrict__ Wm, const float* __restrict__ Bm,
    const float* __restrict__ Wsd, const float* __restrict__ Bsd,
    float* __restrict__ odm, float* __restrict__ ods)
{
  __shared__ float smem[14944];
  if ((int)blockIdx.x < ngru)
    dev_gru(smem, blockIdx.x, h, hbf, x_t, z, Wih, Whh, bih, bhh);
  else
    dev_dec(smem, blockIdx.x - ngru, zg3, p3, gam, bet, Wm,Bm,Wsd,Bsd, odm, ods);
}

__global__ __launch_bounds__(256) void k_final(const float* __restrict__ lklp,
                                               float* __restrict__ out){
  __shared__ float red[4];
  float s = 0.f;
  for (int i = threadIdx.x; i < 460; i += 256) s += lklp[i];
  s = wsum_(s);
  if ((threadIdx.x&63)==0) red[threadIdx.x>>6]=s;
  __syncthreads();
  if (threadIdx.x==0) out[0] = red[0]+red[1]+red[2]+red[3];
}

extern "C" void kernel_launch(void* const* d_in, const int* in_sizes, int n_in,
                              void* d_out, int out_size, void* d_ws, size_t ws_size,
                              hipStream_t stream)
{
  (void)in_sizes; (void)n_in; (void)out_size; (void)ws_size;
  const float* states=(const float*)d_in[0];
  const float* eps   =(const float*)d_in[1];
  const float *m1W1=(const float*)d_in[2],  *m1b1=(const float*)d_in[3],
              *m1W2=(const float*)d_in[4],  *m1b2=(const float*)d_in[5],
              *m1g =(const float*)d_in[6],  *m1bt=(const float*)d_in[7];
  const float *m2W1=(const float*)d_in[8],  *m2b1=(const float*)d_in[9],
              *m2W2=(const float*)d_in[10], *m2b2=(const float*)d_in[11],
              *m2g =(const float*)d_in[12], *m2bt=(const float*)d_in[13];
  const float *m3W1=(const float*)d_in[14], *m3b1=(const float*)d_in[15],
              *m3W2=(const float*)d_in[16], *m3b2=(const float*)d_in[17],
              *m3g =(const float*)d_in[18], *m3bt=(const float*)d_in[19];
  const float *emW=(const float*)d_in[20], *emB=(const float*)d_in[21];
  const float *esW=(const float*)d_in[22], *esB=(const float*)d_in[23];
  const float *pmW=(const float*)d_in[24], *pmB=(const float*)d_in[25];
  const float *psW=(const float*)d_in[26], *psB=(const float*)d_in[27];
  const float *dmW=(const float*)d_in[28], *dmB=(const float*)d_in[29];
  const float *dsW=(const float*)d_in[30], *dsB=(const float*)d_in[31];
  const float *gWih=(const float*)d_in[32], *gWhh=(const float*)d_in[33];
  const float *gbih=(const float*)d_in[34], *gbhh=(const float*)d_in[35];
  float* out = (float*)d_out;
  float* ws  = (float*)d_ws;

  // layout (float offsets); bf16 regions 16B-aligned. total 5,219,024 fl = 20.9 MB
  unsigned short* g3b = (unsigned short*)(ws);            // [20][512][192] bf16
  unsigned short* Wbt = (unsigned short*)(ws + 983040);   // [10][4][96][192]
  unsigned short* Wbs = (unsigned short*)(ws + 1351680);  // [4][96][1408]
  unsigned short* hbf = (unsigned short*)(ws + 1622016);  // [22][512][64]
  float* h     = ws + 1982464;       // 720,896
  float* cst   = ws + 2703360;       // 3,840
  float* scsh3 = ws + 2707200;       // 320
  float* zb    = ws + 2707520;       // 47,104
  float* lklp  = ws + 2754624;       // 460 (+pad)
  float* zp1   = ws + 2755088;       // 736
  float* zna   = ws + 2755824;       // 94,208
  float* zp2   = ws + 2850032;       // 8,192
  float* zg3   = ws + 2858224;       // 94,208
  float* zp3   = ws + 2952432;       // 736
  float* raw   = ws + 2953168;       // [4][512][92] = 188,416
  float* scr   = ws + 3141584;       // precompute scratch (2,077,440)
  float* p1p = scr;                  // 14,720
  float* naP = scr + 14720;          // 1,884,160
  float* p2p = scr + 1898880;        // 163,840
  float* p3p = scr + 2062720;        // 14,720

  hipMemsetAsync(h, 0, 720896*sizeof(float), stream);
  hipMemsetAsync(hbf, 0, 720896*sizeof(unsigned short), stream);
  hipMemsetAsync(g3b, 0, 1966080*sizeof(unsigned short), stream);

  // ---- precompute gnn(y,p=0)/gnn(x,p=1), all t (g = p*10+t) ----
  k_stats1<<<dim3(46,20),256,0,stream>>>(states, m1W1, m1b1, m1W2, m1b2, p1p);
  k_pre_edges<<<dim3(512,20),512,0,stream>>>(states, p1p,
      m1W1, m1b1, m1W2, m1b2, m1g, m1bt,
      m2W1, m2b1, m2W2, m2b2, naP, p2p);
  k_pre_node3<<<dim3(46,20),256,0,stream>>>(naP, p2p, m2g, m2bt,
      m3W1, m3b1, m3W2, m3b2, g3b, p3p);
  k_bnred<<<20,256,0,stream>>>(p3p, 46, 1.f/11776.f, m3g, m3bt, scsh3);
  k_wbs<<<2112,256,0,stream>>>(pmW, psW, emW, esW, Wbs);
  k_wbt<<<2880,256,0,stream>>>(pmW, psW, emW, esW, scsh3, Wbt);
  k_cst<<<15,256,0,stream>>>(pmW, psW, emW, esW, scsh3, cst);

  // ---- 3-kernel software-pipelined scan (R6 schedule) ----
  for (int t=0;t<=10;t++){
    int nh = (t<10)?32:0, ne = (t>0)?512:0;
    int tt = (t<10)? t : 0;
    if (nh+ne > 0)
      k_K1<<<nh+ne,256,0,stream>>>(nh, tt,
          g3b, hbf, Wbt, Wbs, cst, raw,
          zb, zp1,
          m1W1+64, m1b1+16, m1W2+128, m1b2+16, m1g+16, m1bt+16,
          m2W1+288, m2b1+16, m2W2+128, m2b2+16, zna, zp2);
    int nf = (t<10)?46:0, nn = (t>0)?46:0;
    if (nf+nn > 0)
      k_K2<<<nf+nn,256,0,stream>>>(nf,
          raw, pmB, psB, emB, esB,
          eps + (size_t)tt*47104, zb, lklp + tt*46,
          m1W1+64, m1b1+16, m1W2+128, m1b2+16, zp1,
          zna, zp2, m2g+16, m2bt+16,
          m3W1+160, m3b1+16, m3W2+128, m3b2+16, zg3, zp3);
    int ng = (t<10)?352:0, nd = (t>0)?352:0;
    int tm1 = (t>0)? t-1 : 0;
    if (ng+nd > 0)
      k_K3<<<ng+nd,256,0,stream>>>(ng,
          h, hbf, states + (size_t)(tt+1)*47104, zb, gWih, gWhh, gbih, gbhh,
          zg3, zp3, m3g+16, m3bt+16, dmW, dmB, dsW, dsB,
          out + (size_t)tm1*45056, out + 450560 + (size_t)tm1*45056);
  }
  k_final<<<1,256,0,stream>>>(lklp, out + 901120);
}

// Round 11
// 820.644 us; speedup vs baseline: 1.2325x; 1.2325x over previous
//
#include <hip/hip_runtime.h>
#include <math.h>

// T=10 B=512 N_ALL=23 N_AGENTS=22 NH=8 E=506 RNN_H=64 Z_DIM=92 IN_H=1592
// R6 schedule (proven 852us): K1(t)=heads(t)[448]+edges(t-1)[512]
//   K2(t)=fused(t)[46]+node3(t-1)[46] ; K3(t)=gru(t)[352]+dec(t-1)[352]
// Only change vs R6: 512-thread precompute edges (104us vs 132us).

__device__ __forceinline__ float elu_(float x){ return x>0.f ? x : __expf(x)-1.f; }
__device__ __forceinline__ float sp_(float x){ return fmaxf(x,0.f)+log1pf(__expf(-fabsf(x))); }
__device__ __forceinline__ float sig_(float x){ return 1.f/(1.f+__expf(-x)); }
__device__ __forceinline__ float wsum_(float v){
  #pragma unroll
  for (int o=32;o;o>>=1) v += __shfl_down(v,o,64);
  return v;
}

// 256-thr block: reduce n x 16 partials -> BN scale/shift in LDS
__device__ __forceinline__ void reduce_bn_(const float* __restrict__ part, int n,
    float invN, const float* __restrict__ gam, const float* __restrict__ bet,
    float* sc, float* sh, float* tmp)
{
  int tid = threadIdx.x;
  int c = tid & 15, i0 = tid >> 4;
  float s = 0.f;
  for (int i = i0; i < n; i += 16) s += part[i*16 + c];
  tmp[i0*16 + c] = s;
  __syncthreads();
  if (tid < 16){
    float v = 0.f;
    #pragma unroll
    for (int i=0;i<16;i++) v += tmp[i*16 + tid];
    tmp[tid] = v;
  }
  __syncthreads();
  if (tid < 8){
    float m = tmp[tid]*invN;
    float var = tmp[8+tid]*invN - m*m;
    float rs = rsqrtf(var + 1e-5f);
    float s2 = rs*gam[tid];
    sc[tid] = s2; sh[tid] = bet[tid] - m*s2;
  }
  __syncthreads();
}

// 256-thr block stats: h[8]/thread -> part[16] = {sum8, sumsq8}
__device__ __forceinline__ void block_stats_(const float h[8], float* __restrict__ part,
                                             float red[][16])
{
  int wid = threadIdx.x >> 6, lane = threadIdx.x & 63;
  #pragma unroll
  for (int j=0;j<8;j++){
    float a = wsum_(h[j]);
    float b = wsum_(h[j]*h[j]);
    if (lane==0){ red[wid][j]=a; red[wid][8+j]=b; }
  }
  __syncthreads();
  if (threadIdx.x < 16)
    part[threadIdx.x] = red[0][threadIdx.x]+red[1][threadIdx.x]
                       +red[2][threadIdx.x]+red[3][threadIdx.x];
}

// ================= device building blocks (256 threads each) =================

// edges (256 thr, smem 5274 fl): BN1-reduce, node MLP1+BN1, edge MLP once,
// receiver pre-BN sums + BN2 stats partials.
__device__ __forceinline__ void dev_edges(
    float* smem, int b, int g, int p, int t,
    const float* __restrict__ src, long sstride, const float* __restrict__ p1,
    const float* __restrict__ nW1b, const float* __restrict__ nb1b,
    const float* __restrict__ nW2b, const float* __restrict__ nb2b,
    const float* __restrict__ g1b, const float* __restrict__ bt1b,
    const float* __restrict__ eW1b, const float* __restrict__ eb1b,
    const float* __restrict__ eW2b, const float* __restrict__ eb2b,
    float* __restrict__ nodeacc, float* __restrict__ p2)
{
  int tid = threadIdx.x;
  float* tmp   = smem;        // 256
  float* sc1   = smem+256;    // 8
  float* sh1   = smem+264;    // 8
  float* xnode = smem+272;    // 207
  float* accs  = smem+480;    // 207
  float* redsq = smem+688;    // 32
  float* le    = smem+720;    // 4554
  {
    const float* pp = p1 + (size_t)g*736;
    int c = tid & 15, i0 = tid >> 4;
    float s = 0.f;
    for (int i=i0;i<46;i+=16) s += pp[i*16+c];
    tmp[i0*16+c] = s;
    __syncthreads();
    if (tid<16){
      float v=0.f;
      #pragma unroll
      for (int i=0;i<16;i++) v += tmp[i*16+tid];
      tmp[tid]=v;
    }
    __syncthreads();
    if (tid<8){
      float m = tmp[tid]*(1.f/11776.f);
      float var = tmp[8+tid]*(1.f/11776.f) - m*m;
      float rs = rsqrtf(var+1e-5f);
      float s2 = rs*g1b[p*8+tid];
      sc1[tid]=s2; sh1[tid]=bt1b[p*8+tid]-m*s2;
    }
    __syncthreads();
  }
  if (tid<23){
    const float* x = src + (size_t)(t+p)*sstride + (size_t)b*92 + tid*4;
    const float* W1 = nW1b+p*32; const float* b1 = nb1b+p*8;
    const float* W2 = nW2b+p*64; const float* b2 = nb2b+p*8;
    float x0=x[0],x1=x[1],x2=x[2],x3=x[3];
    float h1[8];
    #pragma unroll
    for (int j=0;j<8;j++)
      h1[j]=elu_(b1[j]+W1[j*4]*x0+W1[j*4+1]*x1+W1[j*4+2]*x2+W1[j*4+3]*x3);
    #pragma unroll
    for (int j=0;j<8;j++){
      float a=b2[j];
      #pragma unroll
      for (int k=0;k<8;k++) a+=W2[j*8+k]*h1[k];
      xnode[tid*9+j]=elu_(a)*sc1[j]+sh1[j];
    }
  }
  __syncthreads();
  float sq[8]={0,0,0,0,0,0,0,0};
  {
    const float* W1 = eW1b+p*144; const float* b1 = eb1b+p*8;
    const float* W2 = eW2b+p*64;  const float* b2 = eb2b+p*8;
    for (int e=tid; e<506; e+=256){
      int r=e/22, jj=e-r*22;
      int s=jj+(jj>=r?1:0);
      float et0=(jj==0 && r>=1 && r<=21)?1.f:0.f;
      float et1=(r==22)?1.f:0.f;
      float xs[8], xr[8];
      #pragma unroll
      for (int k=0;k<8;k++){ xs[k]=xnode[s*9+k]; xr[k]=xnode[r*9+k]; }
      float h1[8];
      #pragma unroll
      for (int j=0;j<8;j++){
        const float* w=W1+j*18;
        float a=b1[j]+w[16]*et0+w[17]*et1;
        #pragma unroll
        for (int k=0;k<8;k++) a+=w[k]*xs[k];
        #pragma unroll
        for (int k=0;k<8;k++) a+=w[8+k]*xr[k];
        h1[j]=elu_(a);
      }
      #pragma unroll
      for (int j=0;j<8;j++){
        float a=b2[j];
        #pragma unroll
        for (int k=0;k<8;k++) a+=W2[j*8+k]*h1[k];
        float h2=elu_(a);
        le[e*9+j]=h2;
        sq[j]+=h2*h2;
      }
    }
  }
  int wid=tid>>6, lane=tid&63;
  #pragma unroll
  for (int j=0;j<8;j++){
    float v=wsum_(sq[j]);
    if (lane==0) redsq[wid*8+j]=v;
  }
  __syncthreads();
  if (tid<184){
    int r=tid>>3, c=tid&7;
    const float* lp = le + r*198 + c;
    float s=0.f;
    #pragma unroll
    for (int jj=0;jj<22;jj++) s+=lp[jj*9];
    accs[r*9+c]=s;
    nodeacc[((size_t)g*512+b)*184+tid]=s;
  }
  __syncthreads();
  if (tid<16){
    int c=tid&7;
    float s=0.f;
    if (tid<8){
      #pragma unroll
      for (int r=0;r<23;r++) s+=accs[r*9+c];
    } else {
      #pragma unroll
      for (int w=0;w<4;w++) s+=redsq[w*8+c];
    }
    p2[((size_t)g*512+b)*16+tid]=s;
  }
}

// node3: BN2 analytic + MLP3 -> pre-BN g3 rows + BN3 partials
__device__ __forceinline__ void dev_node3(
    int bi, int g, int p,
    const float* __restrict__ nodeacc, const float* __restrict__ p2,
    const float* __restrict__ g2b, const float* __restrict__ bt2b,
    const float* __restrict__ W3b, const float* __restrict__ b3b,
    const float* __restrict__ W4b, const float* __restrict__ b4b,
    float* __restrict__ out, float* __restrict__ p3)
{
  __shared__ float tmp[256], sc2[8], sh2[8];
  __shared__ float red[4][16];
  reduce_bn_(p2 + (size_t)g*8192, 512, 1.f/259072.f, g2b+p*8, bt2b+p*8, sc2, sh2, tmp);
  int row = bi*256 + threadIdx.x;                    // [0, 11776)
  int b = row/23, r = row - b*23;
  const float inv23 = 1.f/23.f;
  const float* na = nodeacc + ((size_t)g*512 + b)*184 + r*8;
  float xk[8];
  #pragma unroll
  for (int k=0;k<8;k++) xk[k] = (na[k]*sc2[k] + 22.f*sh2[k]) * inv23;
  float nt0 = (r<22)?inv23:0.f, nt1 = (r==22)?inv23:0.f;
  const float* W3 = W3b + p*80; const float* b3 = b3b + p*8;
  const float* W4 = W4b + p*64; const float* b4 = b4b + p*8;
  float h1b[8], o[8];
  #pragma unroll
  for (int j=0;j<8;j++){
    const float* w = W3 + j*10;
    float a = b3[j] + w[8]*nt0 + w[9]*nt1;
    #pragma unroll
    for (int k=0;k<8;k++) a += w[k]*xk[k];
    h1b[j] = elu_(a);
  }
  #pragma unroll
  for (int j=0;j<8;j++){
    float a = b4[j];
    #pragma unroll
    for (int k=0;k<8;k++) a += W4[j*8+k]*h1b[k];
    o[j] = elu_(a);
    out[((size_t)g*11776 + row)*8 + j] = o[j];
  }
  block_stats_(o, p3 + ((size_t)g*46 + bi)*16, red);
}

// heads (smem 2704 fl): split-K(14) tiled GEMM tile, BN3 applied in A staging
__device__ __forceinline__ void dev_heads(
    float* smem, int idx, int t,
    const float* __restrict__ gy, const float* __restrict__ gx,
    const float* __restrict__ scsh3, const float* __restrict__ h,
    const float* __restrict__ Wpm, const float* __restrict__ Wps,
    const float* __restrict__ Wem, const float* __restrict__ Wes,
    float* __restrict__ rawp)
{
  int bt = idx & 7, head = (idx>>3)&3, kz = idx>>5;
  const float* W  = (head==0)?Wpm:(head==1)?Wps:(head==2)?Wem:Wes;
  const float* gsel = (head<2)?gy:gx;
  int sel = (head<2) ? t : 10+t;
  float* s3 = smem;                                  // 16
  float (*As)[68]  = (float(*)[68])(smem+16);        // 1088
  float (*Ws)[100] = (float(*)[100])(smem+1104);     // 1600
  int tid = threadIdx.x;
  if (tid < 16) s3[tid] = scsh3[sel*16 + tid];
  int b0 = bt*64;
  int kbeg = kz*114;
  int kend = kbeg+114; if (kend > 1592) kend = 1592;
  int tb = tid & 15, tj = tid >> 4;
  float acc[4][6];
  #pragma unroll
  for (int u=0;u<4;u++)
    #pragma unroll
    for (int vv=0;vv<6;vv++) acc[u][vv]=0.f;
  __syncthreads();
  for (int k0=kbeg; k0<kend; k0+=16){
    #pragma unroll
    for (int l=0;l<4;l++){
      int lin = tid + 256*l;
      int kk = lin & 15, bl = lin >> 4;
      int i = k0 + kk;
      float v = 0.f;
      if (i < kend){
        int bb = b0 + bl;
        if (i < 184){ int c = i&7; v = gsel[bb*184 + i]*s3[c] + s3[8+c]; }
        else { int i2 = i - 184; v = h[(size_t)(i2>>6)*32768 + bb*64 + (i2&63)]; }
      }
      As[kk][bl] = v;
    }
    #pragma unroll
    for (int l=0;l<6;l++){
      int lin = tid + 256*l;
      int kk = lin & 15, jl = lin >> 4;
      int i = k0 + kk;
      float v = 0.f;
      if (i < kend && jl < 92) v = W[jl*1592 + i];
      Ws[kk][jl] = v;
    }
    __syncthreads();
    #pragma unroll
    for (int kk=0;kk<16;kk++){
      float4 a4 = *(const float4*)&As[kk][tb*4];
      float av[4] = {a4.x,a4.y,a4.z,a4.w};
      float2 w01 = *(const float2*)&Ws[kk][tj*6];
      float2 w23 = *(const float2*)&Ws[kk][tj*6+2];
      float2 w45 = *(const float2*)&Ws[kk][tj*6+4];
      float wv[6] = {w01.x,w01.y,w23.x,w23.y,w45.x,w45.y};
      #pragma unroll
      for (int u=0;u<4;u++)
        #pragma unroll
        for (int vv=0;vv<6;vv++) acc[u][vv] += av[u]*wv[vv];
    }
    __syncthreads();
  }
  float* dst = rawp + (size_t)kz*188416 + (size_t)head*47104;
  #pragma unroll
  for (int u=0;u<4;u++){
    int bb = b0 + tb*4 + u;
    #pragma unroll
    for (int vv=0;vv<6;vv++){
      int j = tj*6 + vv;
      if (j < 92) dst[bb*92 + j] = acc[u][vv];
    }
  }
}

// fused (smem 68 fl): split-K combine + bias + sample + KLD + MLP1(set2) stats
__device__ __forceinline__ void dev_fused(
    float* smem, int bi,
    const float* __restrict__ rawp,
    const float* __restrict__ bpm, const float* __restrict__ bps,
    const float* __restrict__ bem, const float* __restrict__ bes,
    const float* __restrict__ eps_t, float* __restrict__ z,
    float* __restrict__ lklp,
    const float* __restrict__ W1, const float* __restrict__ b1,
    const float* __restrict__ W2, const float* __restrict__ b2,
    float* __restrict__ part)
{
  float* redk = smem;                   // 4
  float (*red)[16] = (float(*)[16])(smem+4);  // 64
  int tid = threadIdx.x;
  int row = bi*256 + tid;                            // [0, 11776)
  int bb = row/23, n = row - bb*23;
  (void)bb;
  float pm[4]={0,0,0,0}, ps[4]={0,0,0,0}, em[4]={0,0,0,0}, es[4]={0,0,0,0};
  const float* rp = rawp + 4*(size_t)row;
  #pragma unroll
  for (int zz=0;zz<14;zz++){
    const float* q = rp + (size_t)zz*188416;
    float4 a = *(const float4*)(q);
    float4 bq = *(const float4*)(q + 47104);
    float4 c = *(const float4*)(q + 94208);
    float4 d = *(const float4*)(q + 141312);
    pm[0]+=a.x; pm[1]+=a.y; pm[2]+=a.z; pm[3]+=a.w;
    ps[0]+=bq.x; ps[1]+=bq.y; ps[2]+=bq.z; ps[3]+=bq.w;
    em[0]+=c.x; em[1]+=c.y; em[2]+=c.z; em[3]+=c.w;
    es[0]+=d.x; es[1]+=d.y; es[2]+=d.z; es[3]+=d.w;
  }
  int j0 = 4*n;
  float4 e4 = *(const float4*)(eps_t + 4*(size_t)row);
  float ev[4] = {e4.x, e4.y, e4.z, e4.w};
  float zv[4]; float kl = 0.f;
  #pragma unroll
  for (int q=0;q<4;q++){
    float PM = pm[q] + bpm[j0+q];
    float PS = sp_(ps[q] + bps[j0+q]);
    float EM = em[q] + bem[j0+q];
    float ES = sp_(es[q] + bes[j0+q]);
    zv[q] = EM + ES*ev[q];
    float d = EM - PM;
    kl += 0.5f*(2.f*logf(PS/ES) + (ES*ES + d*d)/(PS*PS) - 1.f);
  }
  float4 zq; zq.x=zv[0]; zq.y=zv[1]; zq.z=zv[2]; zq.w=zv[3];
  *(float4*)(z + 4*(size_t)row) = zq;
  float ks = wsum_(kl);
  if ((tid&63)==0) redk[tid>>6] = ks;
  __syncthreads();
  if (tid==0) lklp[bi] = redk[0]+redk[1]+redk[2]+redk[3];
  float h1[8], h2[8];
  #pragma unroll
  for (int j=0;j<8;j++){
    float a = b1[j] + W1[j*4+0]*zv[0] + W1[j*4+1]*zv[1] + W1[j*4+2]*zv[2] + W1[j*4+3]*zv[3];
    h1[j] = elu_(a);
  }
  #pragma unroll
  for (int j=0;j<8;j++){
    float a = b2[j];
    #pragma unroll
    for (int k=0;k<8;k++) a += W2[j*8+k]*h1[k];
    h2[j] = elu_(a);
  }
  block_stats_(h2, part + (size_t)bi*16, red);
}

// dec (smem 520 fl): BN3 inline via partial reduce, float4 GEMV
__device__ __forceinline__ void dev_dec(
    float* smem, int bi,
    const float* __restrict__ zg3, const float* __restrict__ p3,
    const float* __restrict__ gam, const float* __restrict__ bet,
    const float* __restrict__ Wm, const float* __restrict__ Bm,
    const float* __restrict__ Wsd, const float* __restrict__ Bsd,
    float* __restrict__ odm, float* __restrict__ ods)
{
  int tid = threadIdx.x;
  float* dtmp = smem; float* dsc = smem + 256; float* dsh = smem + 264;
  reduce_bn_(p3, 46, 1.f/11776.f, gam, bet, dsc, dsh, dtmp);
  float4 s0 = {dsc[0],dsc[1],dsc[2],dsc[3]};
  float4 s1 = {dsc[4],dsc[5],dsc[6],dsc[7]};
  float4 t0 = {dsh[0],dsh[1],dsh[2],dsh[3]};
  float4 t1 = {dsh[4],dsh[5],dsh[6],dsh[7]};
  int idx = bi*256 + tid;                            // [0, 90112)
  int hd = idx / 45056; int rem = idx - hd*45056;
  int b = rem / 88, j = rem - b*88;
  const float* W = hd ? Wsd : Wm;
  const float4* a4 = (const float4*)(zg3 + (size_t)b*184);
  const float4* w4 = (const float4*)(W + (size_t)j*184);
  float accv = hd ? Bsd[j] : Bm[j];
  #pragma unroll 2
  for (int i4=0;i4<46;i4++){
    float4 x = a4[i4]; float4 w = w4[i4];
    float4 sc = (i4&1)? s1 : s0; float4 sh = (i4&1)? t1 : t0;
    accv += w.x*(x.x*sc.x+sh.x) + w.y*(x.y*sc.y+sh.y)
          + w.z*(x.z*sc.z+sh.z) + w.w*(x.w*sc.w+sh.w);
  }
  if (hd) ods[(size_t)b*88+j] = sp_(accv);
  else    odm[(size_t)b*88+j] = accv;
}

// gru (smem 14944 fl): conflict-free transposed weights
__device__ __forceinline__ void dev_gru(
    float* smem, int idx,
    float* __restrict__ h, const float* __restrict__ x_t,
    const float* __restrict__ z, const float* __restrict__ Wih,
    const float* __restrict__ Whh, const float* __restrict__ bih,
    const float* __restrict__ bhh)
{
  int tid = threadIdx.x;
  float* WhT  = smem;           // 64*193 = 12352
  float* hs   = smem + 12352;   // 64*36  = 2304
  float* gins = smem + 14656;   // 8*36   = 288
  int a = idx >> 4, yb = idx & 15;
  int b0 = yb*32;
  int c = tid & 63, sq = tid >> 6;
  const float* Wg = Whh + (size_t)a*12288;
  for (int e = tid; e < 12288; e += 256) WhT[(e&63)*193 + (e>>6)] = Wg[e];
  const float* hp_g = h + (size_t)a*32768 + (size_t)b0*64;
  for (int e = tid; e < 2048; e += 256) hs[(e&63)*36 + (e>>6)] = hp_g[e];
  { int s = tid >> 3, k = tid & 7;
    float v = (k<4) ? x_t[(size_t)(b0+s)*92 + a*4 + k]
                    : z[(size_t)(b0+s)*92 + a*4 + (k-4)];
    gins[k*36 + s] = v; }
  float wi0[8], wi1[8], wi2[8];
  const float* Wig = Wih + (size_t)a*1536;
  #pragma unroll
  for (int k=0;k<8;k++){
    wi0[k] = Wig[c*8+k]; wi1[k] = Wig[(64+c)*8+k]; wi2[k] = Wig[(128+c)*8+k];
  }
  float bi0 = bih[a*192+c], bi1 = bih[a*192+64+c], bi2 = bih[a*192+128+c];
  float bh0 = bhh[a*192+c], bh1 = bhh[a*192+64+c], bh2 = bhh[a*192+128+c];
  __syncthreads();
  #pragma unroll
  for (int ps=0; ps<2; ps++){
    int s0 = ps*16 + sq*4;
    float q0[4], q1[4], q2[4];
    #pragma unroll
    for (int i=0;i<4;i++){ q0[i]=bh0; q1[i]=bh1; q2[i]=bh2; }
    for (int k=0;k<64;k++){
      float w0 = WhT[k*193 + c];
      float w1 = WhT[k*193 + 64 + c];
      float w2 = WhT[k*193 + 128 + c];
      float4 hv = *(const float4*)&hs[k*36 + s0];
      float hvv[4] = {hv.x,hv.y,hv.z,hv.w};
      #pragma unroll
      for (int i=0;i<4;i++){ q0[i]+=w0*hvv[i]; q1[i]+=w1*hvv[i]; q2[i]+=w2*hvv[i]; }
    }
    float g0[4], g1[4], g2[4];
    #pragma unroll
    for (int i=0;i<4;i++){ g0[i]=bi0; g1[i]=bi1; g2[i]=bi2; }
    #pragma unroll
    for (int k=0;k<8;k++){
      float4 gv = *(const float4*)&gins[k*36 + s0];
      float gvv[4] = {gv.x,gv.y,gv.z,gv.w};
      #pragma unroll
      for (int i=0;i<4;i++){ g0[i]+=wi0[k]*gvv[i]; g1[i]+=wi1[k]*gvv[i]; g2[i]+=wi2[k]*gvv[i]; }
    }
    float4 hp = *(const float4*)&hs[c*36 + s0];
    float hpv[4] = {hp.x,hp.y,hp.z,hp.w};
    #pragma unroll
    for (int i=0;i<4;i++){
      float rg = sig_(g0[i]+q0[i]);
      float zg = sig_(g1[i]+q1[i]);
      float ng = tanhf(g2[i] + rg*q2[i]);
      h[(size_t)a*32768 + (size_t)(b0+s0+i)*64 + c] = (1.f-zg)*ng + zg*hpv[i];
    }
  }
}

// ================= precompute kernels =================

__global__ __launch_bounds__(256) void k_stats1(
    const float* __restrict__ states,
    const float* __restrict__ W1b, const float* __restrict__ b1b,
    const float* __restrict__ W2b, const float* __restrict__ b2b,
    float* __restrict__ part)
{
  int g = blockIdx.y; int p = g/10; int t = g - p*10;
  const float* W1 = W1b + p*32; const float* b1 = b1b + p*8;
  const float* W2 = W2b + p*64; const float* b2 = b2b + p*8;
  int row = blockIdx.x*256 + threadIdx.x;            // [0, 11776)
  float4 x4 = *(const float4*)(states + (size_t)(t+p)*47104 + 4*(size_t)row);
  float h1[8], h2[8];
  #pragma unroll
  for (int j=0;j<8;j++)
    h1[j] = elu_(b1[j] + W1[j*4+0]*x4.x + W1[j*4+1]*x4.y + W1[j*4+2]*x4.z + W1[j*4+3]*x4.w);
  #pragma unroll
  for (int j=0;j<8;j++){
    float a = b2[j];
    #pragma unroll
    for (int k=0;k<8;k++) a += W2[j*8+k]*h1[k];
    h2[j] = elu_(a);
  }
  __shared__ float red[4][16];
  block_stats_(h2, part + ((size_t)g*46 + blockIdx.x)*16, red);
}

// 512-thread precompute edges (proven fastest shape: 104us for all 20 groups)
__global__ __launch_bounds__(512) void k_pre_edges(
    const float* __restrict__ src, const float* __restrict__ p1,
    const float* __restrict__ nW1b, const float* __restrict__ nb1b,
    const float* __restrict__ nW2b, const float* __restrict__ nb2b,
    const float* __restrict__ g1b, const float* __restrict__ bt1b,
    const float* __restrict__ eW1b, const float* __restrict__ eb1b,
    const float* __restrict__ eW2b, const float* __restrict__ eb2b,
    float* __restrict__ nodeacc, float* __restrict__ p2)
{
  int g = blockIdx.y; int p = g/10; int t = g - p*10; int b = blockIdx.x;
  int tid = threadIdx.x;
  __shared__ float tmp[512];
  __shared__ float sc1[8], sh1[8];
  __shared__ float xnode[207];
  __shared__ float le[4554];
  __shared__ float accs[207];
  __shared__ float redsq[8][8];
  {
    const float* pp = p1 + (size_t)g*736;
    int c = tid & 15, i0 = tid >> 4;
    float s = 0.f;
    for (int i = i0; i < 46; i += 32) s += pp[i*16 + c];
    tmp[i0*16 + c] = s;
    __syncthreads();
    if (tid < 16){
      float v = 0.f;
      #pragma unroll
      for (int i=0;i<32;i++) v += tmp[i*16 + tid];
      tmp[tid] = v;
    }
    __syncthreads();
    if (tid < 8){
      float m = tmp[tid]*(1.f/11776.f);
      float var = tmp[8+tid]*(1.f/11776.f) - m*m;
      float rs = rsqrtf(var + 1e-5f);
      float s2 = rs*g1b[p*8+tid];
      sc1[tid] = s2; sh1[tid] = bt1b[p*8+tid] - m*s2;
    }
    __syncthreads();
  }
  if (tid < 23){
    const float* x = src + (size_t)(t+p)*47104 + (size_t)b*92 + tid*4;
    const float* W1 = nW1b + p*32; const float* b1 = nb1b + p*8;
    const float* W2 = nW2b + p*64; const float* b2 = nb2b + p*8;
    float x0=x[0], x1=x[1], x2=x[2], x3=x[3];
    float h1[8];
    #pragma unroll
    for (int j=0;j<8;j++)
      h1[j] = elu_(b1[j] + W1[j*4]*x0 + W1[j*4+1]*x1 + W1[j*4+2]*x2 + W1[j*4+3]*x3);
    #pragma unroll
    for (int j=0;j<8;j++){
      float a = b2[j];
      #pragma unroll
      for (int k=0;k<8;k++) a += W2[j*8+k]*h1[k];
      xnode[tid*9+j] = elu_(a)*sc1[j] + sh1[j];
    }
  }
  __syncthreads();
  float sq[8] = {0,0,0,0,0,0,0,0};
  if (tid < 506){
    int r = tid/22, jj = tid - r*22;
    int s = jj + (jj>=r ? 1 : 0);
    const float* W1 = eW1b + p*144; const float* b1 = eb1b + p*8;
    const float* W2 = eW2b + p*64;  const float* b2 = eb2b + p*8;
    float et0 = (jj==0 && r>=1 && r<=21) ? 1.f : 0.f;
    float et1 = (r==22) ? 1.f : 0.f;
    float h1[8];
    #pragma unroll
    for (int j=0;j<8;j++){
      const float* w = W1 + j*18;
      float a = b1[j] + w[16]*et0 + w[17]*et1;
      #pragma unroll
      for (int k=0;k<8;k++) a += w[k]*xnode[s*9+k];
      #pragma unroll
      for (int k=0;k<8;k++) a += w[8+k]*xnode[r*9+k];
      h1[j] = elu_(a);
    }
    #pragma unroll
    for (int j=0;j<8;j++){
      float a = b2[j];
      #pragma unroll
      for (int k=0;k<8;k++) a += W2[j*8+k]*h1[k];
      float h2 = elu_(a);
      le[tid*9+j] = h2;
      sq[j] = h2*h2;
    }
  }
  int wid = tid >> 6, lane = tid & 63;
  #pragma unroll
  for (int j=0;j<8;j++){
    float v = wsum_(sq[j]);
    if (lane==0) redsq[wid][j] = v;
  }
  __syncthreads();
  if (tid < 184){
    int r = tid >> 3, c = tid & 7;
    const float* lp = le + r*198 + c;
    float s = 0.f;
    #pragma unroll
    for (int jj=0;jj<22;jj++) s += lp[jj*9];
    accs[r*9+c] = s;
    nodeacc[((size_t)g*512 + b)*184 + tid] = s;
  }
  __syncthreads();
  if (tid < 16){
    int c = tid & 7;
    float s = 0.f;
    if (tid < 8){
      #pragma unroll
      for (int r=0;r<23;r++) s += accs[r*9+c];
    } else {
      #pragma unroll
      for (int w=0;w<8;w++) s += redsq[w][c];
    }
    p2[((size_t)g*512 + b)*16 + tid] = s;
  }
}

__global__ __launch_bounds__(256) void k_pre_node3(
    const float* __restrict__ nodeacc, const float* __restrict__ p2,
    const float* __restrict__ g2, const float* __restrict__ bt2,
    const float* __restrict__ W3, const float* __restrict__ b3,
    const float* __restrict__ W4, const float* __restrict__ b4,
    float* __restrict__ out, float* __restrict__ p3)
{
  int g = blockIdx.y, p = g/10;
  dev_node3(blockIdx.x, g, p, nodeacc, p2, g2, bt2, W3,b3,W4,b4, out, p3);
}

__global__ __launch_bounds__(256) void k_bnred(
    const float* __restrict__ part, int n, float invN,
    const float* __restrict__ gamb, const float* __restrict__ betb,
    float* __restrict__ scsh)
{
  int g = blockIdx.x; int p = g/10;
  int tid = threadIdx.x;
  __shared__ float tmp[256];
  const float* pp = part + (size_t)g*n*16;
  int c = tid & 15, i0 = tid >> 4;
  float s = 0.f;
  for (int i = i0; i < n; i += 16) s += pp[i*16 + c];
  tmp[i0*16 + c] = s;
  __syncthreads();
  if (tid < 16){
    float v = 0.f;
    #pragma unroll
    for (int i=0;i<16;i++) v += tmp[i*16 + tid];
    tmp[tid] = v;
  }
  __syncthreads();
  if (tid < 8){
    float m = tmp[tid]*invN;
    float var = tmp[8+tid]*invN - m*m;
    float rs = rsqrtf(var + 1e-5f);
    float sc = rs*gamb[p*8+tid];
    scsh[g*16 + tid] = sc;
    scsh[g*16 + 8 + tid] = betb[p*8+tid] - m*sc;
  }
}

// ================= scan kernels (R6 schedule) =================

// K1(t): [0,nh) heads(t), [nh,...) edges(t-1)
__global__ __launch_bounds__(256) void k_K1(
    int nh, int t,
    const float* __restrict__ gy, const float* __restrict__ gx,
    const float* __restrict__ scsh3, const float* __restrict__ h,
    const float* __restrict__ Wpm, const float* __restrict__ Wps,
    const float* __restrict__ Wem, const float* __restrict__ Wes,
    float* __restrict__ rawp,
    const float* __restrict__ zb, const float* __restrict__ zp1,
    const float* __restrict__ nW1, const float* __restrict__ nb1,
    const float* __restrict__ nW2, const float* __restrict__ nb2,
    const float* __restrict__ g1, const float* __restrict__ bt1,
    const float* __restrict__ eW1, const float* __restrict__ eb1,
    const float* __restrict__ eW2, const float* __restrict__ eb2,
    float* __restrict__ zna, float* __restrict__ zp2)
{
  __shared__ float smem[5274];
  if ((int)blockIdx.x < nh)
    dev_heads(smem, blockIdx.x, t, gy, gx, scsh3, h, Wpm,Wps,Wem,Wes, rawp);
  else
    dev_edges(smem, blockIdx.x - nh, 0, 0, 0, zb, 0L, zp1,
              nW1,nb1,nW2,nb2, g1,bt1, eW1,eb1,eW2,eb2, zna, zp2);
}

// K2(t): [0,nf) fused(t), [nf,...) node3(t-1)
__global__ __launch_bounds__(256) void k_K2(
    int nf,
    const float* __restrict__ rawp,
    const float* __restrict__ bpm, const float* __restrict__ bps,
    const float* __restrict__ bem, const float* __restrict__ bes,
    const float* __restrict__ eps_t, float* __restrict__ z,
    float* __restrict__ lklp,
    const float* __restrict__ W1, const float* __restrict__ b1,
    const float* __restrict__ W2, const float* __restrict__ b2,
    float* __restrict__ part,
    const float* __restrict__ zna, const float* __restrict__ zp2,
    const float* __restrict__ g2, const float* __restrict__ bt2,
    const float* __restrict__ W3, const float* __restrict__ b3,
    const float* __restrict__ W4, const float* __restrict__ b4,
    float* __restrict__ zg3, float* __restrict__ zp3)
{
  __shared__ float smem[68];
  if ((int)blockIdx.x < nf)
    dev_fused(smem, blockIdx.x, rawp, bpm,bps,bem,bes, eps_t, z, lklp, W1,b1,W2,b2, part);
  else
    dev_node3(blockIdx.x - nf, 0, 0, zna, zp2, g2, bt2, W3,b3,W4,b4, zg3, zp3);
}

// K3(t): [0,ngru) gru(t), [ngru,...) dec(t-1)
__global__ __launch_bounds__(256) void k_K3(
    int ngru,
    float* __restrict__ h, const float* __restrict__ x_t,
    const float* __restrict__ z, const float* __restrict__ Wih,
    const float* __restrict__ Whh, const float* __restrict__ bih,
    const float* __restrict__ bhh,
    const float* __restrict__ zg3, const float* __restrict__ p3,
    const float* __restrict__ gam, const float* __restrict__ bet,
    const float* __restrict__ Wm, const float* __restrict__ Bm,
    const float* __restrict__ Wsd, const float* __restrict__ Bsd,
    float* __restrict__ odm, float* __restrict__ ods)
{
  __shared__ float smem[14944];
  if ((int)blockIdx.x < ngru)
    dev_gru(smem, blockIdx.x, h, x_t, z, Wih, Whh, bih, bhh);
  else
    dev_dec(smem, blockIdx.x - ngru, zg3, p3, gam, bet, Wm,Bm,Wsd,Bsd, odm, ods);
}

__global__ __launch_bounds__(256) void k_final(const float* __restrict__ lklp,
                                               float* __restrict__ out){
  __shared__ float red[4];
  float s = 0.f;
  for (int i = threadIdx.x; i < 460; i += 256) s += lklp[i];
  s = wsum_(s);
  if ((threadIdx.x&63)==0) red[threadIdx.x>>6]=s;
  __syncthreads();
  if (threadIdx.x==0) out[0] = red[0]+red[1]+red[2]+red[3];
}

extern "C" void kernel_launch(void* const* d_in, const int* in_sizes, int n_in,
                              void* d_out, int out_size, void* d_ws, size_t ws_size,
                              hipStream_t stream)
{
  (void)in_sizes; (void)n_in; (void)out_size; (void)ws_size;
  const float* states=(const float*)d_in[0];
  const float* eps   =(const float*)d_in[1];
  const float *m1W1=(const float*)d_in[2],  *m1b1=(const float*)d_in[3],
              *m1W2=(const float*)d_in[4],  *m1b2=(const float*)d_in[5],
              *m1g =(const float*)d_in[6],  *m1bt=(const float*)d_in[7];
  const float *m2W1=(const float*)d_in[8],  *m2b1=(const float*)d_in[9],
              *m2W2=(const float*)d_in[10], *m2b2=(const float*)d_in[11],
              *m2g =(const float*)d_in[12], *m2bt=(const float*)d_in[13];
  const float *m3W1=(const float*)d_in[14], *m3b1=(const float*)d_in[15],
              *m3W2=(const float*)d_in[16], *m3b2=(const float*)d_in[17],
              *m3g =(const float*)d_in[18], *m3bt=(const float*)d_in[19];
  const float *emW=(const float*)d_in[20], *emB=(const float*)d_in[21];
  const float *esW=(const float*)d_in[22], *esB=(const float*)d_in[23];
  const float *pmW=(const float*)d_in[24], *pmB=(const float*)d_in[25];
  const float *psW=(const float*)d_in[26], *psB=(const float*)d_in[27];
  const float *dmW=(const float*)d_in[28], *dmB=(const float*)d_in[29];
  const float *dsW=(const float*)d_in[30], *dsB=(const float*)d_in[31];
  const float *gWih=(const float*)d_in[32], *gWhh=(const float*)d_in[33];
  const float *gbih=(const float*)d_in[34], *gbhh=(const float*)d_in[35];
  float* out = (float*)d_out;
  float* ws  = (float*)d_ws;

  // persistent (floats) — total 5,488,844 fl = 21.96 MB
  float* g3    = ws;                 // [20][11776][8] = 1,884,160 (pre-BN3)
  float* h     = ws + 1884160;       // 720,896
  float* zb    = ws + 2605056;       // 47,104
  float* lklp  = ws + 2652160;       // 460
  float* scsh3 = ws + 2652620;       // 320
  float* zp1   = ws + 2652940;       // 736
  float* zna   = ws + 2653676;       // 94,208
  float* zp2   = ws + 2747884;       // 8,192
  float* zg3   = ws + 2756076;       // 94,208
  float* zp3   = ws + 2850284;       // 736
  float* rawp  = ws + 2851020;       // [14][4][512][92] = 2,637,824
  // precompute aliases inside rawp (dead once scan starts)
  float* p1p = rawp;                 // [20][46][16]   = 14,720
  float* naP = rawp + 14720;         // [20][512][184] = 1,884,160
  float* p2p = rawp + 1898880;       // [20][512][16]  = 163,840
  float* p3p = rawp + 2062720;       // [20][46][16]   = 14,720

  hipMemsetAsync(h, 0, 720896*sizeof(float), stream);

  // ---- precompute gnn(y,p=0)/gnn(x,p=1), all t (g = p*10+t) ----
  k_stats1<<<dim3(46,20),256,0,stream>>>(states, m1W1, m1b1, m1W2, m1b2, p1p);
  k_pre_edges<<<dim3(512,20),512,0,stream>>>(states, p1p,
      m1W1, m1b1, m1W2, m1b2, m1g, m1bt,
      m2W1, m2b1, m2W2, m2b2, naP, p2p);
  k_pre_node3<<<dim3(46,20),256,0,stream>>>(naP, p2p, m2g, m2bt,
      m3W1, m3b1, m3W2, m3b2, g3, p3p);
  k_bnred<<<20,256,0,stream>>>(p3p, 46, 1.f/11776.f, m3g, m3bt, scsh3);

  // ---- software-pipelined scan: 11 iterations ----
  for (int t=0;t<=10;t++){
    int nh = (t<10)?448:0, ne = (t>0)?512:0;
    int tt = (t<10)? t : 0;
    if (nh+ne > 0)
      k_K1<<<nh+ne,256,0,stream>>>(nh, tt,
          g3 + (size_t)tt*94208, g3 + 942080 + (size_t)tt*94208,
          scsh3, h, pmW, psW, emW, esW, rawp,
          zb, zp1,
          m1W1+64, m1b1+16, m1W2+128, m1b2+16, m1g+16, m1bt+16,
          m2W1+288, m2b1+16, m2W2+128, m2b2+16, zna, zp2);
    int nf = (t<10)?46:0, nn = (t>0)?46:0;
    if (nf+nn > 0)
      k_K2<<<nf+nn,256,0,stream>>>(nf,
          rawp, pmB, psB, emB, esB,
          eps + (size_t)tt*47104, zb, lklp + tt*46,
          m1W1+64, m1b1+16, m1W2+128, m1b2+16, zp1,
          zna, zp2, m2g+16, m2bt+16,
          m3W1+160, m3b1+16, m3W2+128, m3b2+16, zg3, zp3);
    int ng = (t<10)?352:0, nd = (t>0)?352:0;
    int tm1 = (t>0)? t-1 : 0;
    if (ng+nd > 0)
      k_K3<<<ng+nd,256,0,stream>>>(ng,
          h, states + (size_t)(tt+1)*47104, zb, gWih, gWhh, gbih, gbhh,
          zg3, zp3, m3g+16, m3bt+16, dmW, dmB, dsW, dsB,
          out + (size_t)tm1*45056, out + 450560 + (size_t)tm1*45056);
  }
  k_final<<<1,256,0,stream>>>(lklp, out + 901120);
}